// Round 7
// baseline (486.902 us; speedup 1.0000x reference)
//
#include <hip/hip_runtime.h>
#include <stdint.h>

#define BATCH 64
#define SLEN 512
#define HID 128
#define NHEAD 4
#define DPROJ 512            // HID * NHEAD
#define MTOT (BATCH * SLEN)  // 32768
#define SCALE 0.08838834764831845f

using short8 = __attribute__((ext_vector_type(8))) short;
using f32x4  = __attribute__((ext_vector_type(4))) float;
using u32x4  = __attribute__((ext_vector_type(4))) unsigned int;
using u32x2  = __attribute__((ext_vector_type(2))) unsigned int;
using us4    = __attribute__((ext_vector_type(4))) unsigned short;

__device__ __forceinline__ unsigned short f2bf(float f) {
  unsigned int u = __float_as_uint(f);
  u += 0x7fffu + ((u >> 16) & 1u);   // round-to-nearest-even
  return (unsigned short)(u >> 16);
}

// ---------------------------------------------------------------------------
// Kernel 0: prep = weight cast+transpose (Wq pre-scaled by 1/sqrt(H)) AND
// enc fp32->bf16 cast.
// ---------------------------------------------------------------------------
__global__ __launch_bounds__(256) void prep_kernel(
    const float* __restrict__ Wq,
    const float* __restrict__ Wk,
    const float* __restrict__ Wv,
    const float* __restrict__ Wo,
    const float* __restrict__ enc,
    unsigned short* __restrict__ WT,
    unsigned short* __restrict__ WoT,
    unsigned short* __restrict__ encb)
{
  if (blockIdx.x < 1024) {
    int idx = blockIdx.x * 256 + threadIdx.x;
    int z = idx >> 16;
    int i = idx & 65535;
    if (z < 3) {
      const float* W = (z == 0) ? Wq : (z == 1) ? Wk : Wv;
      float scale = (z == 0) ? SCALE : 1.0f;   // fold softmax scale into Wq
      int k = i >> 9;
      int n = i & 511;
      WT[(size_t)z * 65536 + (size_t)n * 128 + k] = f2bf(W[i] * scale);
    } else {
      int k = i >> 7;
      int n = i & 127;
      WoT[(size_t)n * 512 + k] = f2bf(Wo[i]);
    }
  } else {
    size_t tid = (size_t)(blockIdx.x - 1024) * 256 + threadIdx.x;  // 0..524287
    const float* s = enc + tid * 8;
    f32x4 a0 = *(const f32x4*)(s);
    f32x4 a1 = *(const f32x4*)(s + 4);
    short8 v;
    #pragma unroll
    for (int j = 0; j < 4; ++j) v[j] = (short)f2bf(a0[j]);
    #pragma unroll
    for (int j = 0; j < 4; ++j) v[4 + j] = (short)f2bf(a1[j]);
    *(short8*)(encb + tid * 8) = v;
  }
}

// ---------------------------------------------------------------------------
// Kernel 0b: pack mask int32 -> bitmask. 4 ints/thread (4 ballot rounds of
// 64 consecutive ints each); lanes 0..3 write one u64 each.
// ---------------------------------------------------------------------------
__global__ __launch_bounds__(256) void maskpack_kernel(
    const int* __restrict__ mask,
    unsigned int* __restrict__ mbits)
{
  const int l = threadIdx.x & 63;
  size_t wavebase = (size_t)blockIdx.x * 1024 + (threadIdx.x >> 6) * 256;
  unsigned long long b0 = __ballot(mask[wavebase + 0 * 64 + l] != 0);
  unsigned long long b1 = __ballot(mask[wavebase + 1 * 64 + l] != 0);
  unsigned long long b2 = __ballot(mask[wavebase + 2 * 64 + l] != 0);
  unsigned long long b3 = __ballot(mask[wavebase + 3 * 64 + l] != 0);
  if (l < 4) {
    unsigned long long v = (l & 2) ? ((l & 1) ? b3 : b2) : ((l & 1) ? b1 : b0);
    *(unsigned long long*)(mbits + (wavebase >> 5) + l * 2) = v;
  }
}

// ---------------------------------------------------------------------------
// Kernel 1: QKV projection. Grid (4 heads, 256 mt, 3 z) = 3072 blocks.
// A-fragments read directly from global (tile L1/L2-hot); only B in LDS
// (34.8 KB -> 4 blocks/CU). One barrier per block.
// Q/K: swapped-operand MFMA (reg axis = d) -> packed us4 stores.
// V: written transposed (reg axis = s).
// ---------------------------------------------------------------------------
__global__ __launch_bounds__(256, 4) void qkv_kernel(
    const unsigned short* __restrict__ encb,  // (M,128) bf16
    const unsigned short* __restrict__ WT,    // (3,512,128) bf16 n-major
    unsigned short* __restrict__ Qh,
    unsigned short* __restrict__ Kh,
    unsigned short* __restrict__ Vt)
{
  const int nt = blockIdx.x;   // 0..3 == head
  const int mt = blockIdx.y;   // 0..255
  const int z  = blockIdx.z;   // 0..2
  const int t = threadIdx.x;
  const int lane = t & 63;
  const int w = t >> 6;
  const int quad = lane >> 4;
  const int l16 = lane & 15;

  __shared__ __align__(16) unsigned short Bld[128 * 136];  // W rows (n) x K=128

  const int m0 = mt * 128, n0 = nt * 128;
  const int wm = (w >> 1) * 64, wn = (w & 1) * 64;
  const unsigned short* Wz = WT + (size_t)z * DPROJ * HID;

  // stage B tile (128 x 128)
  #pragma unroll
  for (int i = 0; i < 8; ++i) {
    int idx = i * 256 + t;
    int row = idx >> 4;
    int col = (idx & 15) << 3;
    *(u32x4*)(Bld + row * 136 + col) =
        *(const u32x4*)(Wz + (size_t)(n0 + row) * HID + col);
  }
  __syncthreads();

  f32x4 acc[4][4];
  #pragma unroll
  for (int mi = 0; mi < 4; ++mi)
    #pragma unroll
    for (int ni = 0; ni < 4; ++ni)
      acc[mi][ni] = f32x4{0.f, 0.f, 0.f, 0.f};

  #pragma unroll
  for (int kk = 0; kk < 4; ++kk) {
    short8 a[4], bb[4];
    #pragma unroll
    for (int mi = 0; mi < 4; ++mi)
      a[mi] = *(const short8*)(encb + (size_t)(m0 + wm + mi * 16 + l16) * HID + kk * 32 + quad * 8);
    #pragma unroll
    for (int ni = 0; ni < 4; ++ni)
      bb[ni] = *(const short8*)(Bld + (wn + ni * 16 + l16) * 136 + kk * 32 + quad * 8);
    if (z < 2) {
      #pragma unroll
      for (int mi = 0; mi < 4; ++mi)
        #pragma unroll
        for (int ni = 0; ni < 4; ++ni)
          acc[mi][ni] = __builtin_amdgcn_mfma_f32_16x16x32_bf16(bb[ni], a[mi], acc[mi][ni], 0, 0, 0);
    } else {
      #pragma unroll
      for (int mi = 0; mi < 4; ++mi)
        #pragma unroll
        for (int ni = 0; ni < 4; ++ni)
          acc[mi][ni] = __builtin_amdgcn_mfma_f32_16x16x32_bf16(a[mi], bb[ni], acc[mi][ni], 0, 0, 0);
    }
  }

  if (z < 2) {
    // D[n][m]: col(l16)=m-within-16, row(quad*4+r)=d-within-16
    unsigned short* outz = ((z == 0) ? Qh : Kh) + (size_t)nt * MTOT * HID;
    #pragma unroll
    for (int mi = 0; mi < 4; ++mi)
      #pragma unroll
      for (int ni = 0; ni < 4; ++ni) {
        int m = m0 + wm + mi * 16 + l16;
        int dbase = wn + ni * 16 + quad * 4;
        us4 pk;
        #pragma unroll
        for (int r = 0; r < 4; ++r) pk[r] = f2bf(acc[mi][ni][r]);
        *(us4*)(outz + (size_t)m * HID + dbase) = pk;
      }
  } else {
    // D[m][n]: reg axis = s (4 consecutive) -> Vt[(nt*B+b)*128 + d][s]
    #pragma unroll
    for (int mi = 0; mi < 4; ++mi)
      #pragma unroll
      for (int ni = 0; ni < 4; ++ni) {
        int row0 = m0 + wm + mi * 16 + quad * 4;
        int b = row0 >> 9, s = row0 & 511;
        int d = wn + ni * 16 + l16;
        us4 pk;
        #pragma unroll
        for (int r = 0; r < 4; ++r) pk[r] = f2bf(acc[mi][ni][r]);
        *(us4*)(Vt + ((size_t)(nt * BATCH + b) * HID + d) * SLEN + s) = pk;
      }
  }
}

// ---------------------------------------------------------------------------
// Kernel 2: flash attention. 128-q tile, 512 thr, XCD swizzle, K/V register
// prefetch. Pld uses XOR-swizzled stride-64 layout -> LDS 52224 B -> 3
// blocks/CU. PV uses swapped operands (D[d][q]) -> packed us4 ctx stores;
// rowsum via mfma(ones, P) keeps q on the col axis.
// ---------------------------------------------------------------------------
__global__ __launch_bounds__(512, 6) void attn_kernel(
    const unsigned short* __restrict__ Qh,   // (NH, M, 128)
    const unsigned short* __restrict__ Kh,   // (NH, M, 128)
    const unsigned short* __restrict__ Vt,   // (NH, B, 128, S)
    const unsigned int* __restrict__ mbits,  // (B, S, 16)
    unsigned short* __restrict__ ctx)        // (M, 512)
{
  const int lin = blockIdx.x;              // 0..1023
  const int work = (lin & 7) * 128 + (lin >> 3);
  const int qt = work & 3;
  const int h  = (work >> 2) & 3;
  const int b  = work >> 4;

  const int t = threadIdx.x;
  const int lane = t & 63;
  const int w = t >> 6;                    // 0..7
  const int quad = lane >> 4;
  const int l16 = lane & 15;

  __shared__ __align__(16) unsigned short Kld[64 * 136];   // 17408 B
  __shared__ __align__(16) unsigned short Vtld[128 * 72];  // 18432 B
  __shared__ __align__(16) unsigned short Pld[128 * 64];   // 16384 B (swizzled)

  const int q0 = qt * 128;
  const size_t rowbase = (size_t)b * SLEN;
  const unsigned short* kbase0 = Kh + ((size_t)h * MTOT + rowbase) * HID;
  const unsigned short* vbase  = Vt + (size_t)(h * BATCH + b) * HID * SLEN;
  const unsigned int* mrow = mbits + (size_t)b * SLEN * 16;

  const int k_key = t >> 4, k_col = (t & 15) << 3;   // +32 keys at i=1
  const int v_d   = t >> 3, v_cc  = (t & 7) << 3;    // +64 d at i=1

  short8 qa[4];
  {
    const unsigned short* qbase =
        Qh + ((size_t)h * MTOT + rowbase + q0 + w * 16 + l16) * HID + quad * 8;
    #pragma unroll
    for (int kk = 0; kk < 4; ++kk)
      qa[kk] = *(const short8*)(qbase + kk * 32);
  }

  short8 ones;
  #pragma unroll
  for (int j = 0; j < 8; ++j) ones[j] = (short)0x3F80;  // bf16 1.0

  f32x4 oc[8], oc9;
  #pragma unroll
  for (int nd = 0; nd < 8; ++nd) oc[nd] = f32x4{0.f, 0.f, 0.f, 0.f};
  oc9 = f32x4{0.f, 0.f, 0.f, 0.f};

  // prefetch chunk 0 into registers
  u32x4 kreg[2], vreg[2];
  #pragma unroll
  for (int i = 0; i < 2; ++i) {
    kreg[i] = *(const u32x4*)(kbase0 + (size_t)(k_key + i * 32) * HID + k_col);
    vreg[i] = *(const u32x4*)(vbase + (size_t)(v_d + i * 64) * SLEN + v_cc);
  }

  for (int c0 = 0; c0 < SLEN; c0 += 64) {
    if (c0) __syncthreads();   // prev chunk's LDS reads complete
    #pragma unroll
    for (int i = 0; i < 2; ++i) {
      *(u32x4*)(Kld + (k_key + i * 32) * 136 + k_col) = kreg[i];
      *(u32x4*)(Vtld + (v_d + i * 64) * 72 + v_cc) = vreg[i];
    }
    __syncthreads();
    if (c0 + 64 < SLEN) {
      #pragma unroll
      for (int i = 0; i < 2; ++i) {
        kreg[i] = *(const u32x4*)(kbase0 + (size_t)(c0 + 64 + k_key + i * 32) * HID + k_col);
        vreg[i] = *(const u32x4*)(vbase + (size_t)(v_d + i * 64) * SLEN + c0 + 64 + v_cc);
      }
    }

    // mask bits for this chunk
    u32x2 mw[4];
    #pragma unroll
    for (int r = 0; r < 4; ++r) {
      int qrow = q0 + w * 16 + quad * 4 + r;
      mw[r] = *(const u32x2*)(mrow + (size_t)qrow * 16 + (c0 >> 5));
    }

    // S = Q K^T (scale folded into Q)
    f32x4 sc[4];
    #pragma unroll
    for (int ni = 0; ni < 4; ++ni) sc[ni] = f32x4{0.f, 0.f, 0.f, 0.f};
    #pragma unroll
    for (int kk = 0; kk < 4; ++kk) {
      #pragma unroll
      for (int ni = 0; ni < 4; ++ni) {
        short8 bb = *(const short8*)(Kld + (ni * 16 + l16) * 136 + kk * 32 + quad * 8);
        sc[ni] = __builtin_amdgcn_mfma_f32_16x16x32_bf16(qa[kk], bb, sc[ni], 0, 0, 0);
      }
    }

    // p = mask ? exp(s) : 0 ; write to swizzled Pld (wave-private rows)
    #pragma unroll
    for (int ni = 0; ni < 4; ++ni) {
      int bit = (ni & 1) * 16 + l16;
      #pragma unroll
      for (int r = 0; r < 4; ++r) {
        unsigned wsel = (ni < 2) ? mw[r][0] : mw[r][1];
        float e = __expf(sc[ni][r]);
        float p = ((wsel >> bit) & 1u) ? e : 0.f;
        int rowp = w * 16 + quad * 4 + r;
        int cg = (ni * 2 + (l16 >> 3)) ^ (rowp & 7);
        Pld[rowp * 64 + cg * 8 + (l16 & 7)] = f2bf(p);
      }
    }
    __threadfence_block();

    // O += V^T-as-A @ P-as-B  -> D[d][q]; rowsum via ones-as-A
    #pragma unroll
    for (int kb = 0; kb < 2; ++kb) {
      int rowr = w * 16 + l16;
      int cg = (kb * 4 + quad) ^ (l16 & 7);
      short8 a = *(const short8*)(Pld + rowr * 64 + cg * 8);
      #pragma unroll
      for (int nd = 0; nd < 8; ++nd) {
        short8 bv = *(const short8*)(Vtld + (nd * 16 + l16) * 72 + kb * 32 + quad * 8);
        oc[nd] = __builtin_amdgcn_mfma_f32_16x16x32_bf16(bv, a, oc[nd], 0, 0, 0);
      }
      oc9 = __builtin_amdgcn_mfma_f32_16x16x32_bf16(ones, a, oc9, 0, 0, 0);
    }
  }

  // D[d][q]: col=l16 -> q = q0 + w*16 + l16 ; row=quad*4+r -> d = nd*16+quad*4+r
  float rcp = 1.0f / oc9[0];
  int qrow = q0 + w * 16 + l16;
  unsigned short* crow = ctx + (rowbase + qrow) * DPROJ + h * HID;
  #pragma unroll
  for (int nd = 0; nd < 8; ++nd) {
    us4 pk;
    #pragma unroll
    for (int r = 0; r < 4; ++r) pk[r] = f2bf(oc[nd][r] * rcp);
    *(us4*)(crow + nd * 16 + quad * 4) = pk;
  }
}

// ---------------------------------------------------------------------------
// Kernel 3: fused output projection + residual + LayerNorm. ZERO LDS, zero
// barriers: A-frags from the wave's own ctx rows; B-frags from the 128 KB
// L2-resident WoT. Wave w owns rows m0+w*16..+15 across all 128 cols; LN
// reduction is quad-local shuffles.
// ---------------------------------------------------------------------------
__global__ __launch_bounds__(256, 2) void oproj_ln_kernel(
    const unsigned short* __restrict__ ctx,   // (M,512) bf16
    const unsigned short* __restrict__ WoT,   // (128,512) bf16 n-major
    const float* __restrict__ enc,            // (M,128) fp32
    const float* __restrict__ gamma,
    const float* __restrict__ beta,
    float* __restrict__ out)                  // (M,128) fp32
{
  const int m0 = blockIdx.x * 64;
  const int t = threadIdx.x;
  const int lane = t & 63;
  const int w = t >> 6;
  const int quad = lane >> 4;
  const int l16 = lane & 15;

  const unsigned short* arow = ctx + (size_t)(m0 + w * 16 + l16) * DPROJ;

  f32x4 acc[8];
  #pragma unroll
  for (int ni = 0; ni < 8; ++ni) acc[ni] = f32x4{0.f, 0.f, 0.f, 0.f};

  #pragma unroll
  for (int kc = 0; kc < 16; ++kc) {
    short8 a = *(const short8*)(arow + kc * 32 + quad * 8);
    #pragma unroll
    for (int ni = 0; ni < 8; ++ni) {
      short8 bb = *(const short8*)(WoT + (size_t)(ni * 16 + l16) * DPROJ + kc * 32 + quad * 8);
      acc[ni] = __builtin_amdgcn_mfma_f32_16x16x32_bf16(a, bb, acc[ni], 0, 0, 0);
    }
  }

  // rows m = m0 + w*16 + quad*4 + r ; cols n = ni*16 + l16
  float g[8], be[8];
  #pragma unroll
  for (int ni = 0; ni < 8; ++ni) {
    g[ni] = gamma[ni * 16 + l16];
    be[ni] = beta[ni * 16 + l16];
  }

  float val[8][4];
  #pragma unroll
  for (int r = 0; r < 4; ++r) {
    int m = m0 + w * 16 + quad * 4 + r;
    const float* erow = enc + (size_t)m * HID;
    float s = 0.f, s2 = 0.f;
    #pragma unroll
    for (int ni = 0; ni < 8; ++ni) {
      float v = acc[ni][r] + erow[ni * 16 + l16];
      val[ni][r] = v;
      s += v;
      s2 += v * v;
    }
    #pragma unroll
    for (int off = 1; off < 16; off <<= 1) {
      s  += __shfl_xor(s, off, 64);
      s2 += __shfl_xor(s2, off, 64);
    }
    float mean = s * (1.f / 128.f);
    float var = s2 * (1.f / 128.f) - mean * mean;
    float rstd = rsqrtf(var + 1e-6f);
    float* orow = out + (size_t)m * HID;
    #pragma unroll
    for (int ni = 0; ni < 8; ++ni)
      orow[ni * 16 + l16] = g[ni] * (val[ni][r] - mean) * rstd + be[ni];
  }
}

// ---------------------------------------------------------------------------
// ws layout (elements):
//   WT   : 3*512*128 shorts        WoT : 128*512 shorts
//   Qh   : 4*M*128 shorts          Kh  : 4*M*128 shorts
//   Vt   : 4*64*128*512 shorts     ctx : M*512 shorts
//   encb : M*128 shorts (fp32-sized slot)
//   mbits: 64*512*16 u32           (~153.6 MB total)
// ---------------------------------------------------------------------------
extern "C" void kernel_launch(void* const* d_in, const int* in_sizes, int n_in,
                              void* d_out, int out_size, void* d_ws, size_t ws_size,
                              hipStream_t stream) {
  const float* enc   = (const float*)d_in[0];
  const int*   mask  = (const int*)d_in[1];
  const float* Wq    = (const float*)d_in[2];
  const float* Wk    = (const float*)d_in[3];
  const float* Wv    = (const float*)d_in[4];
  const float* Wo    = (const float*)d_in[5];
  const float* gamma = (const float*)d_in[6];
  const float* beta  = (const float*)d_in[7];
  float* out = (float*)d_out;

  unsigned short* WT  = (unsigned short*)d_ws;
  unsigned short* WoT = WT + (size_t)3 * DPROJ * HID;
  unsigned short* Qh  = WoT + (size_t)HID * DPROJ;
  unsigned short* Kh  = Qh + (size_t)NHEAD * MTOT * HID;
  unsigned short* Vt  = Kh + (size_t)NHEAD * MTOT * HID;
  unsigned short* ctx = Vt + (size_t)NHEAD * MTOT * HID;
  unsigned short* encb = ctx + (size_t)MTOT * DPROJ;
  unsigned int* mbits = (unsigned int*)(encb + (size_t)MTOT * HID * 2);

  prep_kernel<<<3072, 256, 0, stream>>>(Wq, Wk, Wv, Wo, enc, WT, WoT, encb);
  maskpack_kernel<<<16384, 256, 0, stream>>>(mask, mbits);
  qkv_kernel<<<dim3(4, 256, 3), 256, 0, stream>>>(encb, WT, Qh, Kh, Vt);
  attn_kernel<<<1024, 512, 0, stream>>>(Qh, Kh, Vt, mbits, ctx);
  oproj_ln_kernel<<<MTOT / 64, 256, 0, stream>>>(ctx, WoT, enc, gamma, beta, out);
}

// Round 8
// 246.475 us; speedup vs baseline: 1.9755x; 1.9755x over previous
//
#include <hip/hip_runtime.h>
#include <stdint.h>

#define BATCH 64
#define SLEN 512
#define HID 128
#define NHEAD 4
#define DPROJ 512            // HID * NHEAD
#define MTOT (BATCH * SLEN)  // 32768
#define SCALE 0.08838834764831845f

using short8 = __attribute__((ext_vector_type(8))) short;
using f32x4  = __attribute__((ext_vector_type(4))) float;
using u32x4  = __attribute__((ext_vector_type(4))) unsigned int;
using u32x2  = __attribute__((ext_vector_type(2))) unsigned int;
using us4    = __attribute__((ext_vector_type(4))) unsigned short;

__device__ __forceinline__ unsigned short f2bf(float f) {
  unsigned int u = __float_as_uint(f);
  u += 0x7fffu + ((u >> 16) & 1u);   // round-to-nearest-even
  return (unsigned short)(u >> 16);
}

// ---------------------------------------------------------------------------
// Kernel 0: prep. blocks 0..1023: weight cast+transpose (Wq pre-scaled).
// blocks 1024..3071: enc fp32->bf16. blocks 3072..19455: mask -> bitmask.
// ---------------------------------------------------------------------------
__global__ __launch_bounds__(256) void prep_kernel(
    const float* __restrict__ Wq,
    const float* __restrict__ Wk,
    const float* __restrict__ Wv,
    const float* __restrict__ Wo,
    const float* __restrict__ enc,
    const int* __restrict__ mask,
    unsigned short* __restrict__ WT,
    unsigned short* __restrict__ WoT,
    unsigned short* __restrict__ encb,
    unsigned int* __restrict__ mbits)
{
  if (blockIdx.x < 1024) {
    int idx = blockIdx.x * 256 + threadIdx.x;
    int z = idx >> 16;
    int i = idx & 65535;
    if (z < 3) {
      const float* W = (z == 0) ? Wq : (z == 1) ? Wk : Wv;
      float scale = (z == 0) ? SCALE : 1.0f;   // fold softmax scale into Wq
      int k = i >> 9;
      int n = i & 511;
      WT[(size_t)z * 65536 + (size_t)n * 128 + k] = f2bf(W[i] * scale);
    } else {
      int k = i >> 7;
      int n = i & 127;
      WoT[(size_t)n * 512 + k] = f2bf(Wo[i]);
    }
  } else if (blockIdx.x < 3072) {
    size_t tid = (size_t)(blockIdx.x - 1024) * 256 + threadIdx.x;  // 0..524287
    const float* s = enc + tid * 8;
    f32x4 a0 = *(const f32x4*)(s);
    f32x4 a1 = *(const f32x4*)(s + 4);
    short8 v;
    #pragma unroll
    for (int j = 0; j < 4; ++j) v[j] = (short)f2bf(a0[j]);
    #pragma unroll
    for (int j = 0; j < 4; ++j) v[4 + j] = (short)f2bf(a1[j]);
    *(short8*)(encb + tid * 8) = v;
  } else {
    const int l = threadIdx.x & 63;
    size_t wavebase = (size_t)(blockIdx.x - 3072) * 1024 + (threadIdx.x >> 6) * 256;
    unsigned long long b0 = __ballot(mask[wavebase + 0 * 64 + l] != 0);
    unsigned long long b1 = __ballot(mask[wavebase + 1 * 64 + l] != 0);
    unsigned long long b2 = __ballot(mask[wavebase + 2 * 64 + l] != 0);
    unsigned long long b3 = __ballot(mask[wavebase + 3 * 64 + l] != 0);
    if (l < 4) {
      unsigned long long v = (l & 2) ? ((l & 1) ? b3 : b2) : ((l & 1) ? b1 : b0);
      *(unsigned long long*)(mbits + (wavebase >> 5) + l * 2) = v;
    }
  }
}

// ---------------------------------------------------------------------------
// Kernel 1: QKV projection. Grid (4 heads, 256 mt); z-loop INSIDE the block
// (A-tile staged once, reused 3x). Full K=128 in LDS.
// Q/K: swapped-operand MFMA (D[n][m], reg axis = d) -> packed us4 stores.
// V: written transposed (reg axis = s).
// ---------------------------------------------------------------------------
__global__ __launch_bounds__(256) void qkv_kernel(
    const unsigned short* __restrict__ encb,  // (M,128) bf16
    const unsigned short* __restrict__ WT,    // (3,512,128) bf16 n-major
    unsigned short* __restrict__ Qh,
    unsigned short* __restrict__ Kh,
    unsigned short* __restrict__ Vt)
{
  const int nt = blockIdx.x;   // 0..3 == head
  const int mt = blockIdx.y;   // 0..255
  const int t = threadIdx.x;
  const int lane = t & 63;
  const int w = t >> 6;
  const int quad = lane >> 4;
  const int l16 = lane & 15;

  __shared__ __align__(16) unsigned short Ald[128 * 136];  // enc rows x K=128
  __shared__ __align__(16) unsigned short Bld[128 * 136];  // W rows (n) x K

  const int m0 = mt * 128, n0 = nt * 128;
  const int wm = (w >> 1) * 64, wn = (w & 1) * 64;

  // stage A once: 128x128 shorts = 2048 vec8, 8 per thread
  #pragma unroll
  for (int i = 0; i < 8; ++i) {
    int idx = i * 256 + t;
    int row = idx >> 4;
    int col = (idx & 15) << 3;
    *(u32x4*)(Ald + row * 136 + col) =
        *(const u32x4*)(encb + (size_t)(m0 + row) * HID + col);
  }

  for (int z = 0; z < 3; ++z) {
    __syncthreads();   // z=0: A visible; z>0: prev z's frag reads done
    const unsigned short* Wz = WT + (size_t)z * DPROJ * HID;
    #pragma unroll
    for (int i = 0; i < 8; ++i) {
      int idx = i * 256 + t;
      int row = idx >> 4;
      int col = (idx & 15) << 3;
      *(u32x4*)(Bld + row * 136 + col) =
          *(const u32x4*)(Wz + (size_t)(n0 + row) * HID + col);
    }
    __syncthreads();

    f32x4 acc[4][4];
    #pragma unroll
    for (int mi = 0; mi < 4; ++mi)
      #pragma unroll
      for (int ni = 0; ni < 4; ++ni)
        acc[mi][ni] = f32x4{0.f, 0.f, 0.f, 0.f};

    #pragma unroll
    for (int kk = 0; kk < 4; ++kk) {
      short8 a[4], bb[4];
      #pragma unroll
      for (int mi = 0; mi < 4; ++mi)
        a[mi] = *(const short8*)(Ald + (wm + mi * 16 + l16) * 136 + kk * 32 + quad * 8);
      #pragma unroll
      for (int ni = 0; ni < 4; ++ni)
        bb[ni] = *(const short8*)(Bld + (wn + ni * 16 + l16) * 136 + kk * 32 + quad * 8);
      if (z < 2) {
        #pragma unroll
        for (int mi = 0; mi < 4; ++mi)
          #pragma unroll
          for (int ni = 0; ni < 4; ++ni)
            acc[mi][ni] = __builtin_amdgcn_mfma_f32_16x16x32_bf16(bb[ni], a[mi], acc[mi][ni], 0, 0, 0);
      } else {
        #pragma unroll
        for (int mi = 0; mi < 4; ++mi)
          #pragma unroll
          for (int ni = 0; ni < 4; ++ni)
            acc[mi][ni] = __builtin_amdgcn_mfma_f32_16x16x32_bf16(a[mi], bb[ni], acc[mi][ni], 0, 0, 0);
      }
    }

    if (z < 2) {
      // D[n][m]: col(l16)=m-within-16, row(quad*4+r)=d-within-16
      unsigned short* outz = ((z == 0) ? Qh : Kh) + (size_t)nt * MTOT * HID;
      #pragma unroll
      for (int mi = 0; mi < 4; ++mi)
        #pragma unroll
        for (int ni = 0; ni < 4; ++ni) {
          int m = m0 + wm + mi * 16 + l16;
          int dbase = wn + ni * 16 + quad * 4;
          us4 pk;
          #pragma unroll
          for (int r = 0; r < 4; ++r) pk[r] = f2bf(acc[mi][ni][r]);
          *(us4*)(outz + (size_t)m * HID + dbase) = pk;
        }
    } else {
      // D[m][n]: reg axis = s (4 consecutive) -> Vt[(nt*B+b)*128 + d][s]
      #pragma unroll
      for (int mi = 0; mi < 4; ++mi)
        #pragma unroll
        for (int ni = 0; ni < 4; ++ni) {
          int row0 = m0 + wm + mi * 16 + quad * 4;
          int b = row0 >> 9, s = row0 & 511;
          int d = wn + ni * 16 + l16;
          us4 pk;
          #pragma unroll
          for (int r = 0; r < 4; ++r) pk[r] = f2bf(acc[mi][ni][r]);
          *(us4*)(Vt + ((size_t)(nt * BATCH + b) * HID + d) * SLEN + s) = pk;
        }
    }
  }
}

// ---------------------------------------------------------------------------
// Kernel 2: flash attention. 128-q tile, 512 thr, XCD swizzle, K/V register
// prefetch. Pld XOR-swizzled (52224 B total LDS). PV swapped operands
// (D[d][q]) -> packed us4 ctx stores; rowsum via mfma(ones, P).
// launch_bounds (512,4): VGPR cap 128 — (512,6) forced cap 85 -> spills
// (R7: VGPR 40, +600 MB scratch traffic, 3x slowdown). Do not raise.
// ---------------------------------------------------------------------------
__global__ __launch_bounds__(512, 4) void attn_kernel(
    const unsigned short* __restrict__ Qh,   // (NH, M, 128)
    const unsigned short* __restrict__ Kh,   // (NH, M, 128)
    const unsigned short* __restrict__ Vt,   // (NH, B, 128, S)
    const unsigned int* __restrict__ mbits,  // (B, S, 16)
    unsigned short* __restrict__ ctx)        // (M, 512)
{
  const int lin = blockIdx.x;              // 0..1023
  const int work = (lin & 7) * 128 + (lin >> 3);
  const int qt = work & 3;
  const int h  = (work >> 2) & 3;
  const int b  = work >> 4;

  const int t = threadIdx.x;
  const int lane = t & 63;
  const int w = t >> 6;                    // 0..7
  const int quad = lane >> 4;
  const int l16 = lane & 15;

  __shared__ __align__(16) unsigned short Kld[64 * 136];   // 17408 B
  __shared__ __align__(16) unsigned short Vtld[128 * 72];  // 18432 B
  __shared__ __align__(16) unsigned short Pld[128 * 64];   // 16384 B (swizzled)

  const int q0 = qt * 128;
  const size_t rowbase = (size_t)b * SLEN;
  const unsigned short* kbase0 = Kh + ((size_t)h * MTOT + rowbase) * HID;
  const unsigned short* vbase  = Vt + (size_t)(h * BATCH + b) * HID * SLEN;
  const unsigned int* mrow = mbits + (size_t)b * SLEN * 16;

  const int k_key = t >> 4, k_col = (t & 15) << 3;   // +32 keys at i=1
  const int v_d   = t >> 3, v_cc  = (t & 7) << 3;    // +64 d at i=1

  short8 qa[4];
  {
    const unsigned short* qbase =
        Qh + ((size_t)h * MTOT + rowbase + q0 + w * 16 + l16) * HID + quad * 8;
    #pragma unroll
    for (int kk = 0; kk < 4; ++kk)
      qa[kk] = *(const short8*)(qbase + kk * 32);
  }

  short8 ones;
  #pragma unroll
  for (int j = 0; j < 8; ++j) ones[j] = (short)0x3F80;  // bf16 1.0

  f32x4 oc[8], oc9;
  #pragma unroll
  for (int nd = 0; nd < 8; ++nd) oc[nd] = f32x4{0.f, 0.f, 0.f, 0.f};
  oc9 = f32x4{0.f, 0.f, 0.f, 0.f};

  // prefetch chunk 0 into registers
  u32x4 kreg[2], vreg[2];
  #pragma unroll
  for (int i = 0; i < 2; ++i) {
    kreg[i] = *(const u32x4*)(kbase0 + (size_t)(k_key + i * 32) * HID + k_col);
    vreg[i] = *(const u32x4*)(vbase + (size_t)(v_d + i * 64) * SLEN + v_cc);
  }

  for (int c0 = 0; c0 < SLEN; c0 += 64) {
    if (c0) __syncthreads();   // prev chunk's LDS reads complete
    #pragma unroll
    for (int i = 0; i < 2; ++i) {
      *(u32x4*)(Kld + (k_key + i * 32) * 136 + k_col) = kreg[i];
      *(u32x4*)(Vtld + (v_d + i * 64) * 72 + v_cc) = vreg[i];
    }
    __syncthreads();
    if (c0 + 64 < SLEN) {
      #pragma unroll
      for (int i = 0; i < 2; ++i) {
        kreg[i] = *(const u32x4*)(kbase0 + (size_t)(c0 + 64 + k_key + i * 32) * HID + k_col);
        vreg[i] = *(const u32x4*)(vbase + (size_t)(v_d + i * 64) * SLEN + c0 + 64 + v_cc);
      }
    }

    // mask bits for this chunk
    u32x2 mw[4];
    #pragma unroll
    for (int r = 0; r < 4; ++r) {
      int qrow = q0 + w * 16 + quad * 4 + r;
      mw[r] = *(const u32x2*)(mrow + (size_t)qrow * 16 + (c0 >> 5));
    }

    // S = Q K^T (scale folded into Q)
    f32x4 sc[4];
    #pragma unroll
    for (int ni = 0; ni < 4; ++ni) sc[ni] = f32x4{0.f, 0.f, 0.f, 0.f};
    #pragma unroll
    for (int kk = 0; kk < 4; ++kk) {
      #pragma unroll
      for (int ni = 0; ni < 4; ++ni) {
        short8 bb = *(const short8*)(Kld + (ni * 16 + l16) * 136 + kk * 32 + quad * 8);
        sc[ni] = __builtin_amdgcn_mfma_f32_16x16x32_bf16(qa[kk], bb, sc[ni], 0, 0, 0);
      }
    }

    // p = mask ? exp(s) : 0 ; write to swizzled Pld (wave-private rows)
    #pragma unroll
    for (int ni = 0; ni < 4; ++ni) {
      int bit = (ni & 1) * 16 + l16;
      #pragma unroll
      for (int r = 0; r < 4; ++r) {
        unsigned wsel = (ni < 2) ? mw[r][0] : mw[r][1];
        float e = __expf(sc[ni][r]);
        float p = ((wsel >> bit) & 1u) ? e : 0.f;
        int rowp = w * 16 + quad * 4 + r;
        int cg = (ni * 2 + (l16 >> 3)) ^ (rowp & 7);
        Pld[rowp * 64 + cg * 8 + (l16 & 7)] = f2bf(p);
      }
    }
    __threadfence_block();

    // O += V^T-as-A @ P-as-B  -> D[d][q]; rowsum via ones-as-A
    #pragma unroll
    for (int kb = 0; kb < 2; ++kb) {
      int rowr = w * 16 + l16;
      int cg = (kb * 4 + quad) ^ (l16 & 7);
      short8 a = *(const short8*)(Pld + rowr * 64 + cg * 8);
      #pragma unroll
      for (int nd = 0; nd < 8; ++nd) {
        short8 bv = *(const short8*)(Vtld + (nd * 16 + l16) * 72 + kb * 32 + quad * 8);
        oc[nd] = __builtin_amdgcn_mfma_f32_16x16x32_bf16(bv, a, oc[nd], 0, 0, 0);
      }
      oc9 = __builtin_amdgcn_mfma_f32_16x16x32_bf16(ones, a, oc9, 0, 0, 0);
    }
  }

  // D[d][q]: col=l16 -> q = q0 + w*16 + l16 ; row=quad*4+r -> d = nd*16+quad*4+r
  float rcp = 1.0f / oc9[0];
  int qrow = q0 + w * 16 + l16;
  unsigned short* crow = ctx + (rowbase + qrow) * DPROJ + h * HID;
  #pragma unroll
  for (int nd = 0; nd < 8; ++nd) {
    us4 pk;
    #pragma unroll
    for (int r = 0; r < 4; ++r) pk[r] = f2bf(oc[nd][r] * rcp);
    *(us4*)(crow + nd * 16 + quad * 4) = pk;
  }
}

// ---------------------------------------------------------------------------
// Kernel 3: fused output projection + residual + LayerNorm.
// Tile 64 rows x 128 cols (full N). Wave w owns rows w*16..+15 across ALL
// 128 cols -> LN reduction is quad-local (shfl_xor < 16). Writes out fp32.
// ---------------------------------------------------------------------------
__global__ __launch_bounds__(256, 4) void oproj_ln_kernel(
    const unsigned short* __restrict__ ctx,   // (M,512) bf16
    const unsigned short* __restrict__ WoT,   // (128,512) bf16 n-major
    const float* __restrict__ enc,            // (M,128) fp32
    const float* __restrict__ gamma,
    const float* __restrict__ beta,
    float* __restrict__ out)                  // (M,128) fp32
{
  const int m0 = blockIdx.x * 64;
  const int t = threadIdx.x;
  const int lane = t & 63;
  const int w = t >> 6;
  const int quad = lane >> 4;
  const int l16 = lane & 15;

  __shared__ __align__(16) unsigned short Actx[64 * 72];   // ctx rows x 64-k
  __shared__ __align__(16) unsigned short Bw[128 * 72];    // WoT rows x 64-k

  f32x4 acc[8];
  #pragma unroll
  for (int ni = 0; ni < 8; ++ni) acc[ni] = f32x4{0.f, 0.f, 0.f, 0.f};

  for (int kc = 0; kc < DPROJ; kc += 64) {
    __syncthreads();
    #pragma unroll
    for (int i = 0; i < 2; ++i) {
      int idx = i * 256 + t;
      int row = idx >> 3;
      int col = (idx & 7) << 3;
      *(u32x4*)(Actx + row * 72 + col) =
          *(const u32x4*)(ctx + (size_t)(m0 + row) * DPROJ + kc + col);
    }
    #pragma unroll
    for (int i = 0; i < 4; ++i) {
      int idx = i * 256 + t;
      int row = idx >> 3;
      int col = (idx & 7) << 3;
      *(u32x4*)(Bw + row * 72 + col) =
          *(const u32x4*)(WoT + (size_t)row * DPROJ + kc + col);
    }
    __syncthreads();
    #pragma unroll
    for (int kk = 0; kk < 2; ++kk) {
      short8 a = *(const short8*)(Actx + (w * 16 + l16) * 72 + kk * 32 + quad * 8);
      #pragma unroll
      for (int ni = 0; ni < 8; ++ni) {
        short8 bb = *(const short8*)(Bw + (ni * 16 + l16) * 72 + kk * 32 + quad * 8);
        acc[ni] = __builtin_amdgcn_mfma_f32_16x16x32_bf16(a, bb, acc[ni], 0, 0, 0);
      }
    }
  }

  // rows m = m0 + w*16 + quad*4 + r ; cols n = ni*16 + l16
  float g[8], be[8];
  #pragma unroll
  for (int ni = 0; ni < 8; ++ni) {
    g[ni] = gamma[ni * 16 + l16];
    be[ni] = beta[ni * 16 + l16];
  }

  float val[8][4];
  #pragma unroll
  for (int r = 0; r < 4; ++r) {
    int m = m0 + w * 16 + quad * 4 + r;
    const float* erow = enc + (size_t)m * HID;
    float s = 0.f, s2 = 0.f;
    #pragma unroll
    for (int ni = 0; ni < 8; ++ni) {
      float v = acc[ni][r] + erow[ni * 16 + l16];
      val[ni][r] = v;
      s += v;
      s2 += v * v;
    }
    #pragma unroll
    for (int off = 1; off < 16; off <<= 1) {
      s  += __shfl_xor(s, off, 64);
      s2 += __shfl_xor(s2, off, 64);
    }
    float mean = s * (1.f / 128.f);
    float var = s2 * (1.f / 128.f) - mean * mean;
    float rstd = rsqrtf(var + 1e-6f);
    float* orow = out + (size_t)m * HID;
    #pragma unroll
    for (int ni = 0; ni < 8; ++ni)
      orow[ni * 16 + l16] = g[ni] * (val[ni][r] - mean) * rstd + be[ni];
  }
}

// ---------------------------------------------------------------------------
// ws layout (elements):
//   WT   : 3*512*128 shorts        WoT : 128*512 shorts
//   Qh   : 4*M*128 shorts          Kh  : 4*M*128 shorts
//   Vt   : 4*64*128*512 shorts     ctx : M*512 shorts
//   encb : M*128 shorts (fp32-sized slot)
//   mbits: 64*512*16 u32           (~153.6 MB total)
// ---------------------------------------------------------------------------
extern "C" void kernel_launch(void* const* d_in, const int* in_sizes, int n_in,
                              void* d_out, int out_size, void* d_ws, size_t ws_size,
                              hipStream_t stream) {
  const float* enc   = (const float*)d_in[0];
  const int*   mask  = (const int*)d_in[1];
  const float* Wq    = (const float*)d_in[2];
  const float* Wk    = (const float*)d_in[3];
  const float* Wv    = (const float*)d_in[4];
  const float* Wo    = (const float*)d_in[5];
  const float* gamma = (const float*)d_in[6];
  const float* beta  = (const float*)d_in[7];
  float* out = (float*)d_out;

  unsigned short* WT  = (unsigned short*)d_ws;
  unsigned short* WoT = WT + (size_t)3 * DPROJ * HID;
  unsigned short* Qh  = WoT + (size_t)HID * DPROJ;
  unsigned short* Kh  = Qh + (size_t)NHEAD * MTOT * HID;
  unsigned short* Vt  = Kh + (size_t)NHEAD * MTOT * HID;
  unsigned short* ctx = Vt + (size_t)NHEAD * MTOT * HID;
  unsigned short* encb = ctx + (size_t)MTOT * DPROJ;
  unsigned int* mbits = (unsigned int*)(encb + (size_t)MTOT * HID * 2);

  prep_kernel<<<19456, 256, 0, stream>>>(Wq, Wk, Wv, Wo, enc, mask, WT, WoT, encb, mbits);
  qkv_kernel<<<dim3(4, 256), 256, 0, stream>>>(encb, WT, Qh, Kh, Vt);
  attn_kernel<<<1024, 512, 0, stream>>>(Qh, Kh, Vt, mbits, ctx);
  oproj_ln_kernel<<<MTOT / 64, 256, 0, stream>>>(ctx, WoT, enc, gamma, beta, out);
}